// Round 6
// baseline (423.743 us; speedup 1.0000x reference)
//
#include <hip/hip_runtime.h>
#include <math.h>

// ---------------------------------------------------------------------------
// GATv2 2-layer GNN, fp32 in/out. N=50000, E=800000, F=128.
//   1. CSR by dst, UNORDERED segments: memset -> count -> atomic offset
//      assignment (no scan; segment order is irrelevant to the aggregate)
//   2. prep_w: split W into bf16 hi/lo, transposed [n][k]
//   3. GEMM v3 (split-bf16 MFMA 3-term): 64-row blocks compute BOTH Wl and
//      Wr products -> X loaded+split exactly once grid-wide
//   4. aggregate: plain-exp softmax, half-wave float4, 16 edges in flight
// ---------------------------------------------------------------------------

typedef short bf16x8 __attribute__((ext_vector_type(8)));
typedef float f32x4 __attribute__((ext_vector_type(4)));

__global__ void count_deg_kernel(const int* __restrict__ dst, int* __restrict__ deg, int E) {
    int i = blockIdx.x * blockDim.x + threadIdx.x;
    if (i < E) atomicAdd(&deg[dst[i]], 1);
}

// Each node gets a disjoint contiguous slice [beg, beg+deg) in arbitrary order.
// counter = &deg[N] (zeroed by the same memset).
__global__ void assign_offsets_kernel(int* __restrict__ deg, int* __restrict__ row_beg,
                                      int* __restrict__ writeidx, int n) {
    int i = blockIdx.x * blockDim.x + threadIdx.x;
    if (i < n) {
        int d = deg[i];
        int beg = atomicAdd(&deg[n], d);  // wave-aggregated by compiler
        row_beg[i] = beg;
        writeidx[i] = beg;
    }
}

__global__ void scatter_edges_kernel(const int* __restrict__ src, const int* __restrict__ dst,
                                     int* __restrict__ writeidx, int* __restrict__ csr_src, int E) {
    int i = blockIdx.x * blockDim.x + threadIdx.x;
    if (i < E) {
        int d = dst[i];
        int pos = atomicAdd(&writeidx[d], 1);
        csr_src[pos] = src[i];
    }
}

// ---------------------------------------------------------------------------
// Split each 128x128 fp32 W into bf16 hi/lo, transposed to [n][k].
// 32 blocks: matrix = blockIdx.x>>3, chunk = blockIdx.x&7 (2048 elems each).
// ---------------------------------------------------------------------------
__global__ __launch_bounds__(256) void prep_w_kernel(
    const float* __restrict__ W0, const float* __restrict__ W1,
    const float* __restrict__ W2, const float* __restrict__ W3,
    short* __restrict__ wt) {
    int mat = blockIdx.x >> 3;
    int chunk = blockIdx.x & 7;
    const float* W = (mat == 0) ? W0 : (mat == 1) ? W1 : (mat == 2) ? W2 : W3;
    short* hi = wt + (size_t)mat * 2 * 16384;
    short* lo = hi + 16384;
    int i0 = chunk * 2048;
    for (int i = i0 + threadIdx.x; i < i0 + 2048; i += 256) {
        int k = i >> 7, n = i & 127;
        float x = W[i];
        unsigned u = __float_as_uint(x);
        unsigned hu = u & 0xFFFF0000u;
        float lf = x - __uint_as_float(hu);
        hi[n * 128 + k] = (short)(hu >> 16);
        lo[n * 128 + k] = (short)(__float_as_uint(lf) >> 16);
    }
}

// ---------------------------------------------------------------------------
// Split-bf16 MFMA GEMM v3: {outL, outR} = X @ {Wl, Wr} + {bl, br}.
// Block: 256 thr, 64 rows, BOTH matrices, all 128 cols. K=128 in 4 chunks.
// X is loaded + hi/lo-split exactly once grid-wide. Wave w owns cols
// [w*32, w*32+32) of both outputs: 4 m-tiles x 2 n-tiles x 2 matrices.
// ---------------------------------------------------------------------------
__global__ __launch_bounds__(256) void gemm_mfma_both_kernel(
    const float* __restrict__ X, const short* __restrict__ wt,
    const float* __restrict__ bl, float* __restrict__ outL,
    const float* __restrict__ br, float* __restrict__ outR,
    int Nrows) {
    const short* WLh = wt;                 // [n][k] bf16 hi
    const short* WLl = wt + 16384;
    const short* WRh = wt + 2 * 16384;
    const short* WRl = wt + 3 * 16384;

    __shared__ short Ahi[64][40];
    __shared__ short Alo[64][40];

    int tid = threadIdx.x;
    int w = tid >> 6, lane = tid & 63, q = lane >> 4, tr = lane & 15;
    int m0 = blockIdx.x * 64;
    int n0 = w * 32;

    f32x4 acc[4][2][2];
    #pragma unroll
    for (int a = 0; a < 4; ++a)
        #pragma unroll
        for (int b = 0; b < 2; ++b)
            #pragma unroll
            for (int c = 0; c < 2; ++c) acc[a][b][c] = (f32x4){0.f, 0.f, 0.f, 0.f};

    for (int kc = 0; kc < 128; kc += 32) {
        // stage + split X tile (64 rows x 32 k): 512 float4s / 256 thr = 2 passes
        #pragma unroll
        for (int pass = 0; pass < 2; ++pass) {
            int flat = pass * 256 + tid;
            int r = flat >> 3;           // 0..63
            int scol = (flat & 7) * 4;   // 0..28
            int gr = m0 + r; if (gr >= Nrows) gr = Nrows - 1;  // stores guarded later
            float4 v = *(const float4*)&X[(size_t)gr * 128 + kc + scol];
            float vv[4] = {v.x, v.y, v.z, v.w};
            short h[4], l[4];
            #pragma unroll
            for (int j = 0; j < 4; ++j) {
                unsigned u = __float_as_uint(vv[j]);
                unsigned hu = u & 0xFFFF0000u;
                float lf = vv[j] - __uint_as_float(hu);
                h[j] = (short)(hu >> 16);
                l[j] = (short)(__float_as_uint(lf) >> 16);
            }
            *(short4*)&Ahi[r][scol] = make_short4(h[0], h[1], h[2], h[3]);
            *(short4*)&Alo[r][scol] = make_short4(l[0], l[1], l[2], l[3]);
        }
        __syncthreads();

        // B fragments: 2 n-tiles x 2 matrices x (hi+lo) = 8 x 16B loads
        bf16x8 bh[2][2], bl8[2][2];
        #pragma unroll
        for (int nt = 0; nt < 2; ++nt) {
            size_t boff = (size_t)(n0 + nt * 16 + tr) * 128 + kc + q * 8;
            bh[0][nt] = *(const bf16x8*)&WLh[boff];
            bl8[0][nt] = *(const bf16x8*)&WLl[boff];
            bh[1][nt] = *(const bf16x8*)&WRh[boff];
            bl8[1][nt] = *(const bf16x8*)&WRl[boff];
        }

        // A fragments from LDS; A[m = lane&15][k = q*8 + j]
        #pragma unroll
        for (int mt = 0; mt < 4; ++mt) {
            bf16x8 ah = *(const bf16x8*)&Ahi[mt * 16 + tr][q * 8];
            bf16x8 al = *(const bf16x8*)&Alo[mt * 16 + tr][q * 8];
            #pragma unroll
            for (int mat = 0; mat < 2; ++mat)
                #pragma unroll
                for (int nt = 0; nt < 2; ++nt) {
                    acc[mt][nt][mat] = __builtin_amdgcn_mfma_f32_16x16x32_bf16(ah, bh[mat][nt], acc[mt][nt][mat], 0, 0, 0);
                    acc[mt][nt][mat] = __builtin_amdgcn_mfma_f32_16x16x32_bf16(ah, bl8[mat][nt], acc[mt][nt][mat], 0, 0, 0);
                    acc[mt][nt][mat] = __builtin_amdgcn_mfma_f32_16x16x32_bf16(al, bh[mat][nt], acc[mt][nt][mat], 0, 0, 0);
                }
        }
        __syncthreads();
    }

    // epilogue: D layout col = lane&15, row = q*4 + reg
    #pragma unroll
    for (int mat = 0; mat < 2; ++mat) {
        float* out = mat ? outR : outL;
        const float* bias = mat ? br : bl;
        #pragma unroll
        for (int nt = 0; nt < 2; ++nt) {
            float bv = bias[n0 + nt * 16 + tr];
            #pragma unroll
            for (int mt = 0; mt < 4; ++mt) {
                #pragma unroll
                for (int r = 0; r < 4; ++r) {
                    int row = m0 + mt * 16 + q * 4 + r;
                    if (row < Nrows)
                        out[(size_t)row * 128 + n0 + nt * 16 + tr] = acc[mt][nt][mat][r] + bv;
                }
            }
        }
    }
}

// ---------------------------------------------------------------------------
// Aggregation v5: plain-exp softmax, half-wave float4, 8 pairs (16 edges)
// in flight per wave for MLP.
// ---------------------------------------------------------------------------
__global__ __launch_bounds__(256) void gat_aggregate_kernel(
    const float* __restrict__ xl, const float* __restrict__ xr,
    const float* __restrict__ att, const float* __restrict__ bias,
    const int* __restrict__ row_beg, const int* __restrict__ deg,
    const int* __restrict__ csr_src,
    float* __restrict__ out, int N, int applyRelu) {
    int wid = threadIdx.x >> 6;
    int lane = threadIdx.x & 63;
    int hlane = lane & 31;
    int half = lane >> 5;
    int node = blockIdx.x * 4 + wid;
    if (node >= N) return;

    const float4* xl4 = (const float4*)xl;
    float4 xrv = ((const float4*)xr)[(size_t)node * 32 + hlane];
    float4 attv = ((const float4*)att)[hlane];

    int beg = row_beg[node];
    int end = beg + deg[node];

    float dsum = 0.f;
    float4 acc = {0.f, 0.f, 0.f, 0.f};

    for (int cbase = beg; cbase < end; cbase += 64) {
        int cnt = end - cbase;
        if (cnt > 64) cnt = 64;
        int myidx = (lane < cnt) ? csr_src[cbase + lane] : 0;  // coalesced
        int npair = cnt >> 1;

        int j = 0;
        for (; j + 8 <= npair; j += 8) {
            int b0 = 2 * j + half;
            int s[8];
            float4 v[8];
            #pragma unroll
            for (int k = 0; k < 8; ++k) s[k] = __shfl(myidx, b0 + 2 * k);
            #pragma unroll
            for (int k = 0; k < 8; ++k) v[k] = xl4[(size_t)s[k] * 32 + hlane];

            float p[8];
            #pragma unroll
            for (int k = 0; k < 8; ++k) {
                float t;
                t = v[k].x + xrv.x; t = t > 0.f ? t : 0.2f * t; p[k] = t * attv.x;
                t = v[k].y + xrv.y; t = t > 0.f ? t : 0.2f * t; p[k] = fmaf(t, attv.y, p[k]);
                t = v[k].z + xrv.z; t = t > 0.f ? t : 0.2f * t; p[k] = fmaf(t, attv.z, p[k]);
                t = v[k].w + xrv.w; t = t > 0.f ? t : 0.2f * t; p[k] = fmaf(t, attv.w, p[k]);
            }
            #pragma unroll
            for (int off = 16; off > 0; off >>= 1) {
                #pragma unroll
                for (int k = 0; k < 8; ++k) p[k] += __shfl_xor(p[k], off);
            }
            float e[8];
            #pragma unroll
            for (int k = 0; k < 8; ++k) e[k] = __expf(p[k]);
            #pragma unroll
            for (int k = 0; k < 8; ++k) {
                dsum += e[k];
                acc.x = fmaf(e[k], v[k].x, acc.x);
                acc.y = fmaf(e[k], v[k].y, acc.y);
                acc.z = fmaf(e[k], v[k].z, acc.z);
                acc.w = fmaf(e[k], v[k].w, acc.w);
            }
        }
        for (; j < npair; ++j) {
            int s = __shfl(myidx, 2 * j + half);
            float4 v = xl4[(size_t)s * 32 + hlane];
            float t, p;
            t = v.x + xrv.x; t = t > 0.f ? t : 0.2f * t; p = t * attv.x;
            t = v.y + xrv.y; t = t > 0.f ? t : 0.2f * t; p = fmaf(t, attv.y, p);
            t = v.z + xrv.z; t = t > 0.f ? t : 0.2f * t; p = fmaf(t, attv.z, p);
            t = v.w + xrv.w; t = t > 0.f ? t : 0.2f * t; p = fmaf(t, attv.w, p);
            #pragma unroll
            for (int off = 16; off > 0; off >>= 1) p += __shfl_xor(p, off);
            float e = __expf(p);
            dsum += e;
            acc.x = fmaf(e, v.x, acc.x);
            acc.y = fmaf(e, v.y, acc.y);
            acc.z = fmaf(e, v.z, acc.z);
            acc.w = fmaf(e, v.w, acc.w);
        }
        if (cnt & 1) {
            // both halves compute identically; only half 0 accumulates
            int s = __shfl(myidx, cnt - 1);
            float4 v = xl4[(size_t)s * 32 + hlane];
            float t, p;
            t = v.x + xrv.x; t = t > 0.f ? t : 0.2f * t; p = t * attv.x;
            t = v.y + xrv.y; t = t > 0.f ? t : 0.2f * t; p = fmaf(t, attv.y, p);
            t = v.z + xrv.z; t = t > 0.f ? t : 0.2f * t; p = fmaf(t, attv.z, p);
            t = v.w + xrv.w; t = t > 0.f ? t : 0.2f * t; p = fmaf(t, attv.w, p);
            #pragma unroll
            for (int off = 16; off > 0; off >>= 1) p += __shfl_xor(p, off);
            float e = (half == 0) ? __expf(p) : 0.f;
            dsum += e;
            acc.x = fmaf(e, v.x, acc.x);
            acc.y = fmaf(e, v.y, acc.y);
            acc.z = fmaf(e, v.z, acc.z);
            acc.w = fmaf(e, v.w, acc.w);
        }
    }

    dsum += __shfl_xor(dsum, 32);
    acc.x += __shfl_xor(acc.x, 32);
    acc.y += __shfl_xor(acc.y, 32);
    acc.z += __shfl_xor(acc.z, 32);
    acc.w += __shfl_xor(acc.w, 32);

    float inv = dsum > 0.f ? 1.f / dsum : 0.f;
    float4 bv = ((const float4*)bias)[hlane];
    float4 o;
    o.x = acc.x * inv + bv.x;
    o.y = acc.y * inv + bv.y;
    o.z = acc.z * inv + bv.z;
    o.w = acc.w * inv + bv.w;
    if (applyRelu) {
        o.x = fmaxf(o.x, 0.f); o.y = fmaxf(o.y, 0.f);
        o.z = fmaxf(o.z, 0.f); o.w = fmaxf(o.w, 0.f);
    }
    if (half == 0) ((float4*)out)[(size_t)node * 32 + hlane] = o;
}

// ---------------------------------------------------------------------------

extern "C" void kernel_launch(void* const* d_in, const int* in_sizes, int n_in,
                              void* d_out, int out_size, void* d_ws, size_t ws_size,
                              hipStream_t stream) {
    const float* x    = (const float*)d_in[0];
    const int* eidx   = (const int*)d_in[1];
    const float* Wl1  = (const float*)d_in[2];
    const float* bl1  = (const float*)d_in[3];
    const float* Wr1  = (const float*)d_in[4];
    const float* br1  = (const float*)d_in[5];
    const float* att1 = (const float*)d_in[6];
    const float* b1   = (const float*)d_in[7];
    const float* Wl2  = (const float*)d_in[8];
    const float* bl2  = (const float*)d_in[9];
    const float* Wr2  = (const float*)d_in[10];
    const float* br2  = (const float*)d_in[11];
    const float* att2 = (const float*)d_in[12];
    const float* b2   = (const float*)d_in[13];

    const int N = in_sizes[0] / 128;
    const int E = in_sizes[1] / 2;
    const int* src = eidx;
    const int* dst = eidx + E;

    // workspace layout
    size_t NF = (size_t)N * 128;
    float* bufA = (float*)d_ws;          // xl
    float* bufB = bufA + NF;             // xr
    float* bufC = bufB + NF;             // h
    int* deg       = (int*)(bufC + NF);  // [N+1] (last slot = global counter)
    int* row_beg   = deg + (N + 1);      // [N]
    int* writeidx  = row_beg + N;        // [N]
    int* csr_src   = writeidx + N;       // [E]
    short* wt      = (short*)(csr_src + E);  // 4 matrices x (hi+lo) x 16384

    float* outF = (float*)d_out;

    // --- CSR build (unordered segments) + W prep ---
    hipMemsetAsync(deg, 0, (size_t)(N + 1) * sizeof(int), stream);
    prep_w_kernel<<<32, 256, 0, stream>>>(Wl1, Wr1, Wl2, Wr2, wt);
    count_deg_kernel<<<(E + 255) / 256, 256, 0, stream>>>(dst, deg, E);
    assign_offsets_kernel<<<(N + 255) / 256, 256, 0, stream>>>(deg, row_beg, writeidx, N);
    scatter_edges_kernel<<<(E + 255) / 256, 256, 0, stream>>>(src, dst, writeidx, csr_src, E);

    dim3 gemmGrid((N + 63) / 64);
    dim3 aggGrid((N + 3) / 4);

    // --- layer 1 ---
    gemm_mfma_both_kernel<<<gemmGrid, 256, 0, stream>>>(x, wt, bl1, bufA, br1, bufB, N);
    gat_aggregate_kernel<<<aggGrid, 256, 0, stream>>>(bufA, bufB, att1, b1, row_beg, deg,
                                                      csr_src, bufC, N, 1);
    // --- layer 2 ---
    gemm_mfma_both_kernel<<<gemmGrid, 256, 0, stream>>>(bufC, wt + 2 * 2 * 16384, bl2, bufA,
                                                        br2, bufB, N);
    gat_aggregate_kernel<<<aggGrid, 256, 0, stream>>>(bufA, bufB, att2, b2, row_beg, deg,
                                                      csr_src, outF, N, 0);
}

// Round 7
// 388.561 us; speedup vs baseline: 1.0905x; 1.0905x over previous
//
#include <hip/hip_runtime.h>
#include <math.h>

// ---------------------------------------------------------------------------
// GATv2 2-layer GNN, fp32 in/out. N=50000, E=800000, F=128.
//   1. CSR by dst, UNORDERED segments (memset -> count -> atomic offsets ->
//      scatter). Segment order is irrelevant to the aggregate.
//   2. prep_w: split W into bf16 hi/lo, transposed [n][k]
//   3. GEMM (split-bf16 MFMA 3-term, round-5 v2): 128-row blocks, wave =
//      128 rows x 32 cols, blockIdx.y selects Wl/Wr
//   4. aggregate: plain-exp softmax, half-wave float4, 4-pair batches
//      (8 edges in flight) + 2/1-pair tail  [round-5 best + tail fix]
// ---------------------------------------------------------------------------

typedef short bf16x8 __attribute__((ext_vector_type(8)));
typedef float f32x4 __attribute__((ext_vector_type(4)));

__global__ void count_deg_kernel(const int* __restrict__ dst, int* __restrict__ deg, int E) {
    int i = blockIdx.x * blockDim.x + threadIdx.x;
    if (i < E) atomicAdd(&deg[dst[i]], 1);
}

// Each node gets a disjoint contiguous slice [beg, beg+deg) in arbitrary order.
// counter = &deg[N] (zeroed by the same memset).
__global__ void assign_offsets_kernel(int* __restrict__ deg, int* __restrict__ row_beg,
                                      int* __restrict__ writeidx, int n) {
    int i = blockIdx.x * blockDim.x + threadIdx.x;
    if (i < n) {
        int d = deg[i];
        int beg = atomicAdd(&deg[n], d);  // wave-aggregated by compiler
        row_beg[i] = beg;
        writeidx[i] = beg;
    }
}

__global__ void scatter_edges_kernel(const int* __restrict__ src, const int* __restrict__ dst,
                                     int* __restrict__ writeidx, int* __restrict__ csr_src, int E) {
    int i = blockIdx.x * blockDim.x + threadIdx.x;
    if (i < E) {
        int d = dst[i];
        int pos = atomicAdd(&writeidx[d], 1);
        csr_src[pos] = src[i];
    }
}

// ---------------------------------------------------------------------------
// Split each 128x128 fp32 W into bf16 hi/lo, transposed to [n][k].
// 32 blocks: matrix = blockIdx.x>>3, chunk = blockIdx.x&7 (2048 elems each).
// ---------------------------------------------------------------------------
__global__ __launch_bounds__(256) void prep_w_kernel(
    const float* __restrict__ W0, const float* __restrict__ W1,
    const float* __restrict__ W2, const float* __restrict__ W3,
    short* __restrict__ wt) {
    int mat = blockIdx.x >> 3;
    int chunk = blockIdx.x & 7;
    const float* W = (mat == 0) ? W0 : (mat == 1) ? W1 : (mat == 2) ? W2 : W3;
    short* hi = wt + (size_t)mat * 2 * 16384;
    short* lo = hi + 16384;
    int i0 = chunk * 2048;
    for (int i = i0 + threadIdx.x; i < i0 + 2048; i += 256) {
        int k = i >> 7, n = i & 127;
        float x = W[i];
        unsigned u = __float_as_uint(x);
        unsigned hu = u & 0xFFFF0000u;
        float lf = x - __uint_as_float(hu);
        hi[n * 128 + k] = (short)(hu >> 16);
        lo[n * 128 + k] = (short)(__float_as_uint(lf) >> 16);
    }
}

// ---------------------------------------------------------------------------
// Split-bf16 MFMA GEMM (round-5 v2, measured): out = X @ W + b.
// Block: 256 thr, tile 128(M) x 128(N), K=128 in 4 chunks of 32.
// Wave w owns ALL 128 rows x cols [w*32, w*32+32): 8 m-tiles x 2 n-tiles.
// ---------------------------------------------------------------------------
__global__ __launch_bounds__(256) void gemm_mfma_dual_kernel(
    const float* __restrict__ X, const short* __restrict__ wt,
    const float* __restrict__ b0, float* __restrict__ out0,
    const float* __restrict__ b1, float* __restrict__ out1,
    int Nrows) {
    const short* WTh = wt + (size_t)blockIdx.y * 2 * 16384;
    const short* WTl = WTh + 16384;
    const float* bias = blockIdx.y ? b1 : b0;
    float* out = blockIdx.y ? out1 : out0;

    __shared__ short Ahi[128][40];
    __shared__ short Alo[128][40];

    int tid = threadIdx.x;
    int w = tid >> 6, lane = tid & 63, q = lane >> 4, tr = lane & 15;
    int m0 = blockIdx.x * 128;
    int n0 = w * 32;

    f32x4 acc[8][2];
    #pragma unroll
    for (int a = 0; a < 8; ++a)
        #pragma unroll
        for (int b = 0; b < 2; ++b) acc[a][b] = (f32x4){0.f, 0.f, 0.f, 0.f};

    int srow = tid >> 3;        // 0..31
    int scol = (tid & 7) * 4;   // 0..28

    for (int kc = 0; kc < 128; kc += 32) {
        // stage + split X tile (128 rows x 32 k)
        #pragma unroll
        for (int pass = 0; pass < 4; ++pass) {
            int r = srow + pass * 32;
            int gr = m0 + r; if (gr >= Nrows) gr = Nrows - 1;  // stores guarded later
            float4 v = *(const float4*)&X[(size_t)gr * 128 + kc + scol];
            float vv[4] = {v.x, v.y, v.z, v.w};
            short h[4], l[4];
            #pragma unroll
            for (int j = 0; j < 4; ++j) {
                unsigned u = __float_as_uint(vv[j]);
                unsigned hu = u & 0xFFFF0000u;
                float lf = vv[j] - __uint_as_float(hu);
                h[j] = (short)(hu >> 16);
                l[j] = (short)(__float_as_uint(lf) >> 16);
            }
            *(short4*)&Ahi[r][scol] = make_short4(h[0], h[1], h[2], h[3]);
            *(short4*)&Alo[r][scol] = make_short4(l[0], l[1], l[2], l[3]);
        }
        __syncthreads();

        // B fragments for this wave's 2 n-tiles
        bf16x8 bh[2], bl[2];
        #pragma unroll
        for (int nt = 0; nt < 2; ++nt) {
            size_t boff = (size_t)(n0 + nt * 16 + tr) * 128 + kc + q * 8;
            bh[nt] = *(const bf16x8*)&WTh[boff];
            bl[nt] = *(const bf16x8*)&WTl[boff];
        }

        // A fragments from LDS, 8 m-tiles; A[m = lane&15][k = q*8 + j]
        #pragma unroll
        for (int mt = 0; mt < 8; ++mt) {
            bf16x8 ah = *(const bf16x8*)&Ahi[mt * 16 + tr][q * 8];
            bf16x8 al = *(const bf16x8*)&Alo[mt * 16 + tr][q * 8];
            #pragma unroll
            for (int nt = 0; nt < 2; ++nt) {
                acc[mt][nt] = __builtin_amdgcn_mfma_f32_16x16x32_bf16(ah, bh[nt], acc[mt][nt], 0, 0, 0);
                acc[mt][nt] = __builtin_amdgcn_mfma_f32_16x16x32_bf16(ah, bl[nt], acc[mt][nt], 0, 0, 0);
                acc[mt][nt] = __builtin_amdgcn_mfma_f32_16x16x32_bf16(al, bh[nt], acc[mt][nt], 0, 0, 0);
            }
        }
        __syncthreads();
    }

    // epilogue: D layout col = lane&15, row = q*4 + reg
    #pragma unroll
    for (int nt = 0; nt < 2; ++nt) {
        float bv = bias[n0 + nt * 16 + tr];
        #pragma unroll
        for (int mt = 0; mt < 8; ++mt) {
            #pragma unroll
            for (int r = 0; r < 4; ++r) {
                int row = m0 + mt * 16 + q * 4 + r;
                if (row < Nrows)
                    out[(size_t)row * 128 + n0 + nt * 16 + tr] = acc[mt][nt][r] + bv;
            }
        }
    }
}

// ---------------------------------------------------------------------------
// Aggregation (round-5 best + 2-pair tail): plain-exp softmax, half-wave
// float4, 4-pair batches (8 edges in flight). VGPR-lean on purpose — 8-pair
// batching measured WORSE (48 VGPR, occupancy 60->43%, 61->75 us).
// ---------------------------------------------------------------------------
__global__ __launch_bounds__(256) void gat_aggregate_kernel(
    const float* __restrict__ xl, const float* __restrict__ xr,
    const float* __restrict__ att, const float* __restrict__ bias,
    const int* __restrict__ row_beg, const int* __restrict__ deg,
    const int* __restrict__ csr_src,
    float* __restrict__ out, int N, int applyRelu) {
    int wid = threadIdx.x >> 6;
    int lane = threadIdx.x & 63;
    int hlane = lane & 31;
    int half = lane >> 5;
    int node = blockIdx.x * 4 + wid;
    if (node >= N) return;

    const float4* xl4 = (const float4*)xl;
    float4 xrv = ((const float4*)xr)[(size_t)node * 32 + hlane];
    float4 attv = ((const float4*)att)[hlane];

    int beg = row_beg[node];
    int end = beg + deg[node];

    float dsum = 0.f;
    float4 acc = {0.f, 0.f, 0.f, 0.f};

    for (int cbase = beg; cbase < end; cbase += 64) {
        int cnt = end - cbase;
        if (cnt > 64) cnt = 64;
        int myidx = (lane < cnt) ? csr_src[cbase + lane] : 0;  // coalesced
        int npair = cnt >> 1;

        int j = 0;
        for (; j + 4 <= npair; j += 4) {
            int b0 = 2 * j + half;
            int s0 = __shfl(myidx, b0 + 0);
            int s1 = __shfl(myidx, b0 + 2);
            int s2 = __shfl(myidx, b0 + 4);
            int s3 = __shfl(myidx, b0 + 6);
            float4 v0 = xl4[(size_t)s0 * 32 + hlane];
            float4 v1 = xl4[(size_t)s1 * 32 + hlane];
            float4 v2 = xl4[(size_t)s2 * 32 + hlane];
            float4 v3 = xl4[(size_t)s3 * 32 + hlane];

            float t, p0, p1, p2, p3;
            t = v0.x + xrv.x; t = t > 0.f ? t : 0.2f * t; p0 = t * attv.x;
            t = v0.y + xrv.y; t = t > 0.f ? t : 0.2f * t; p0 = fmaf(t, attv.y, p0);
            t = v0.z + xrv.z; t = t > 0.f ? t : 0.2f * t; p0 = fmaf(t, attv.z, p0);
            t = v0.w + xrv.w; t = t > 0.f ? t : 0.2f * t; p0 = fmaf(t, attv.w, p0);
            t = v1.x + xrv.x; t = t > 0.f ? t : 0.2f * t; p1 = t * attv.x;
            t = v1.y + xrv.y; t = t > 0.f ? t : 0.2f * t; p1 = fmaf(t, attv.y, p1);
            t = v1.z + xrv.z; t = t > 0.f ? t : 0.2f * t; p1 = fmaf(t, attv.z, p1);
            t = v1.w + xrv.w; t = t > 0.f ? t : 0.2f * t; p1 = fmaf(t, attv.w, p1);
            t = v2.x + xrv.x; t = t > 0.f ? t : 0.2f * t; p2 = t * attv.x;
            t = v2.y + xrv.y; t = t > 0.f ? t : 0.2f * t; p2 = fmaf(t, attv.y, p2);
            t = v2.z + xrv.z; t = t > 0.f ? t : 0.2f * t; p2 = fmaf(t, attv.z, p2);
            t = v2.w + xrv.w; t = t > 0.f ? t : 0.2f * t; p2 = fmaf(t, attv.w, p2);
            t = v3.x + xrv.x; t = t > 0.f ? t : 0.2f * t; p3 = t * attv.x;
            t = v3.y + xrv.y; t = t > 0.f ? t : 0.2f * t; p3 = fmaf(t, attv.y, p3);
            t = v3.z + xrv.z; t = t > 0.f ? t : 0.2f * t; p3 = fmaf(t, attv.z, p3);
            t = v3.w + xrv.w; t = t > 0.f ? t : 0.2f * t; p3 = fmaf(t, attv.w, p3);

            #pragma unroll
            for (int off = 16; off > 0; off >>= 1) {
                p0 += __shfl_xor(p0, off);
                p1 += __shfl_xor(p1, off);
                p2 += __shfl_xor(p2, off);
                p3 += __shfl_xor(p3, off);
            }

            float e0 = __expf(p0);
            float e1 = __expf(p1);
            float e2 = __expf(p2);
            float e3 = __expf(p3);
            dsum += (e0 + e1) + (e2 + e3);
            acc.x = fmaf(e3, v3.x, fmaf(e2, v2.x, fmaf(e1, v1.x, fmaf(e0, v0.x, acc.x))));
            acc.y = fmaf(e3, v3.y, fmaf(e2, v2.y, fmaf(e1, v1.y, fmaf(e0, v0.y, acc.y))));
            acc.z = fmaf(e3, v3.z, fmaf(e2, v2.z, fmaf(e1, v1.z, fmaf(e0, v0.z, acc.z))));
            acc.w = fmaf(e3, v3.w, fmaf(e2, v2.w, fmaf(e1, v1.w, fmaf(e0, v0.w, acc.w))));
        }
        // 2-pair tail step (4 edges)
        if (j + 2 <= npair) {
            int b0 = 2 * j + half;
            int s0 = __shfl(myidx, b0 + 0);
            int s1 = __shfl(myidx, b0 + 2);
            float4 v0 = xl4[(size_t)s0 * 32 + hlane];
            float4 v1 = xl4[(size_t)s1 * 32 + hlane];
            float t, p0, p1;
            t = v0.x + xrv.x; t = t > 0.f ? t : 0.2f * t; p0 = t * attv.x;
            t = v0.y + xrv.y; t = t > 0.f ? t : 0.2f * t; p0 = fmaf(t, attv.y, p0);
            t = v0.z + xrv.z; t = t > 0.f ? t : 0.2f * t; p0 = fmaf(t, attv.z, p0);
            t = v0.w + xrv.w; t = t > 0.f ? t : 0.2f * t; p0 = fmaf(t, attv.w, p0);
            t = v1.x + xrv.x; t = t > 0.f ? t : 0.2f * t; p1 = t * attv.x;
            t = v1.y + xrv.y; t = t > 0.f ? t : 0.2f * t; p1 = fmaf(t, attv.y, p1);
            t = v1.z + xrv.z; t = t > 0.f ? t : 0.2f * t; p1 = fmaf(t, attv.z, p1);
            t = v1.w + xrv.w; t = t > 0.f ? t : 0.2f * t; p1 = fmaf(t, attv.w, p1);
            #pragma unroll
            for (int off = 16; off > 0; off >>= 1) {
                p0 += __shfl_xor(p0, off);
                p1 += __shfl_xor(p1, off);
            }
            float e0 = __expf(p0);
            float e1 = __expf(p1);
            dsum += e0 + e1;
            acc.x = fmaf(e1, v1.x, fmaf(e0, v0.x, acc.x));
            acc.y = fmaf(e1, v1.y, fmaf(e0, v0.y, acc.y));
            acc.z = fmaf(e1, v1.z, fmaf(e0, v0.z, acc.z));
            acc.w = fmaf(e1, v1.w, fmaf(e0, v0.w, acc.w));
            j += 2;
        }
        // 1-pair tail
        if (j < npair) {
            int s = __shfl(myidx, 2 * j + half);
            float4 v = xl4[(size_t)s * 32 + hlane];
            float t, p;
            t = v.x + xrv.x; t = t > 0.f ? t : 0.2f * t; p = t * attv.x;
            t = v.y + xrv.y; t = t > 0.f ? t : 0.2f * t; p = fmaf(t, attv.y, p);
            t = v.z + xrv.z; t = t > 0.f ? t : 0.2f * t; p = fmaf(t, attv.z, p);
            t = v.w + xrv.w; t = t > 0.f ? t : 0.2f * t; p = fmaf(t, attv.w, p);
            #pragma unroll
            for (int off = 16; off > 0; off >>= 1) p += __shfl_xor(p, off);
            float e = __expf(p);
            dsum += e;
            acc.x = fmaf(e, v.x, acc.x);
            acc.y = fmaf(e, v.y, acc.y);
            acc.z = fmaf(e, v.z, acc.z);
            acc.w = fmaf(e, v.w, acc.w);
        }
        // odd tail edge: both halves compute; only half 0 accumulates
        if (cnt & 1) {
            int s = __shfl(myidx, cnt - 1);
            float4 v = xl4[(size_t)s * 32 + hlane];
            float t, p;
            t = v.x + xrv.x; t = t > 0.f ? t : 0.2f * t; p = t * attv.x;
            t = v.y + xrv.y; t = t > 0.f ? t : 0.2f * t; p = fmaf(t, attv.y, p);
            t = v.z + xrv.z; t = t > 0.f ? t : 0.2f * t; p = fmaf(t, attv.z, p);
            t = v.w + xrv.w; t = t > 0.f ? t : 0.2f * t; p = fmaf(t, attv.w, p);
            #pragma unroll
            for (int off = 16; off > 0; off >>= 1) p += __shfl_xor(p, off);
            float e = (half == 0) ? __expf(p) : 0.f;
            dsum += e;
            acc.x = fmaf(e, v.x, acc.x);
            acc.y = fmaf(e, v.y, acc.y);
            acc.z = fmaf(e, v.z, acc.z);
            acc.w = fmaf(e, v.w, acc.w);
        }
    }

    dsum += __shfl_xor(dsum, 32);
    acc.x += __shfl_xor(acc.x, 32);
    acc.y += __shfl_xor(acc.y, 32);
    acc.z += __shfl_xor(acc.z, 32);
    acc.w += __shfl_xor(acc.w, 32);

    float inv = dsum > 0.f ? 1.f / dsum : 0.f;
    float4 bv = ((const float4*)bias)[hlane];
    float4 o;
    o.x = acc.x * inv + bv.x;
    o.y = acc.y * inv + bv.y;
    o.z = acc.z * inv + bv.z;
    o.w = acc.w * inv + bv.w;
    if (applyRelu) {
        o.x = fmaxf(o.x, 0.f); o.y = fmaxf(o.y, 0.f);
        o.z = fmaxf(o.z, 0.f); o.w = fmaxf(o.w, 0.f);
    }
    if (half == 0) ((float4*)out)[(size_t)node * 32 + hlane] = o;
}

// ---------------------------------------------------------------------------

extern "C" void kernel_launch(void* const* d_in, const int* in_sizes, int n_in,
                              void* d_out, int out_size, void* d_ws, size_t ws_size,
                              hipStream_t stream) {
    const float* x    = (const float*)d_in[0];
    const int* eidx   = (const int*)d_in[1];
    const float* Wl1  = (const float*)d_in[2];
    const float* bl1  = (const float*)d_in[3];
    const float* Wr1  = (const float*)d_in[4];
    const float* br1  = (const float*)d_in[5];
    const float* att1 = (const float*)d_in[6];
    const float* b1   = (const float*)d_in[7];
    const float* Wl2  = (const float*)d_in[8];
    const float* bl2  = (const float*)d_in[9];
    const float* Wr2  = (const float*)d_in[10];
    const float* br2  = (const float*)d_in[11];
    const float* att2 = (const float*)d_in[12];
    const float* b2   = (const float*)d_in[13];

    const int N = in_sizes[0] / 128;
    const int E = in_sizes[1] / 2;
    const int* src = eidx;
    const int* dst = eidx + E;

    // workspace layout
    size_t NF = (size_t)N * 128;
    float* bufA = (float*)d_ws;          // xl
    float* bufB = bufA + NF;             // xr
    float* bufC = bufB + NF;             // h
    int* deg       = (int*)(bufC + NF);  // [N+1] (last slot = global counter)
    int* row_beg   = deg + (N + 1);      // [N]
    int* writeidx  = row_beg + N;        // [N]
    int* csr_src   = writeidx + N;       // [E]
    short* wt      = (short*)(csr_src + E);  // 4 matrices x (hi+lo) x 16384

    float* outF = (float*)d_out;

    // --- CSR build (unordered segments) + W prep ---
    hipMemsetAsync(deg, 0, (size_t)(N + 1) * sizeof(int), stream);
    prep_w_kernel<<<32, 256, 0, stream>>>(Wl1, Wr1, Wl2, Wr2, wt);
    count_deg_kernel<<<(E + 255) / 256, 256, 0, stream>>>(dst, deg, E);
    assign_offsets_kernel<<<(N + 255) / 256, 256, 0, stream>>>(deg, row_beg, writeidx, N);
    scatter_edges_kernel<<<(E + 255) / 256, 256, 0, stream>>>(src, dst, writeidx, csr_src, E);

    dim3 gemmGrid((N + 127) / 128, 2);
    dim3 aggGrid((N + 3) / 4);

    // --- layer 1 ---
    gemm_mfma_dual_kernel<<<gemmGrid, 256, 0, stream>>>(x, wt, bl1, bufA, br1, bufB, N);
    gat_aggregate_kernel<<<aggGrid, 256, 0, stream>>>(bufA, bufB, att1, b1, row_beg, deg,
                                                      csr_src, bufC, N, 1);
    // --- layer 2 ---
    gemm_mfma_dual_kernel<<<gemmGrid, 256, 0, stream>>>(bufC, wt + 2 * 2 * 16384, bl2, bufA,
                                                        br2, bufB, N);
    gat_aggregate_kernel<<<aggGrid, 256, 0, stream>>>(bufA, bufB, att2, b2, row_beg, deg,
                                                      csr_src, outF, N, 0);
}